// Round 1
// baseline (1487.560 us; speedup 1.0000x reference)
//
#include <hip/hip_runtime.h>

// Problem constants (from reference setup_inputs)
#define N_NODES 50000
#define N_EDGES 800000
#define XF 512
#define EF 64
#define UF 128
#define HS 1024
#define CIN 832           // 512 + 3*64 + 128
#define NGRAPH 8
#define EPS_BN 1e-5f
#define M_PAD 50048       // 391 * 128  (GEMM row padding)

typedef __bf16 bf16x8 __attribute__((ext_vector_type(8)));
typedef short s16x8 __attribute__((ext_vector_type(8)));
typedef float f32x4 __attribute__((ext_vector_type(4)));

__device__ __forceinline__ short f2bf(float f) {
  unsigned u = __float_as_uint(f);
  u += 0x7FFFu + ((u >> 16) & 1u);   // round-to-nearest-even (finite inputs)
  return (short)(u >> 16);
}
__device__ __forceinline__ float bf2f(short s) {
  return __uint_as_float(((unsigned)(unsigned short)s) << 16);
}

// async global->LDS, 16B per lane; LDS dest must be uniform-base + lane*16
#define ASYNC_CP(gp, lp)                                                      \
  __builtin_amdgcn_global_load_lds(                                           \
      (__attribute__((address_space(1))) void*)(gp),                          \
      (__attribute__((address_space(3))) void*)(lp), 16, 0, 0)

// ---------------------------------------------------------------------------
// 1) Edge scatter: ssum (atomicAdd), smax (atomicMax on order-preserving uint
//    encoding), cnt (per-edge atomicAdd). Thread t -> edge t/64, feat t%64.
// ---------------------------------------------------------------------------
__global__ void scatter_kernel(const float* __restrict__ ea,
                               const int* __restrict__ col,
                               float* __restrict__ ssum,
                               unsigned* __restrict__ smax,
                               float* __restrict__ cnt) {
  int t = blockIdx.x * 256 + threadIdx.x;   // grid sized exactly E*64
  int e = t >> 6;
  int f = t & 63;
  int c = col[e];                           // broadcast within each wave
  float v = ea[(size_t)e * EF + f];
  atomicAdd(&ssum[(size_t)c * EF + f], v);
  unsigned b = __float_as_uint(v);
  unsigned enc = b ^ ((b >> 31) ? 0xFFFFFFFFu : 0x80000000u);
  atomicMax(&smax[(size_t)c * EF + f], enc);
  if (f == 0) atomicAdd(&cnt[c], 1.0f);
}

// ---------------------------------------------------------------------------
// 2) fp32 -> bf16 weight cast
// ---------------------------------------------------------------------------
__global__ void cast_kernel(const float* __restrict__ w, short* __restrict__ o,
                            int n) {
  int i = blockIdx.x * 256 + threadIdx.x;
  if (i < n) o[i] = f2bf(w[i]);
}

// ---------------------------------------------------------------------------
// 3) Assemble h = [x | u[batch] | smax | smean | ssum] as bf16, pad rows = 0
//    One block per row, 832 threads (13 waves), wave-uniform section branches.
// ---------------------------------------------------------------------------
__global__ __launch_bounds__(832) void assemble_kernel(
    const float* __restrict__ x, const float* __restrict__ u,
    const int* __restrict__ batch, const float* __restrict__ cnt,
    const unsigned* __restrict__ smax, const float* __restrict__ ssum,
    short* __restrict__ h) {
  int n = blockIdx.x;
  int c = threadIdx.x;
  float val = 0.f;
  if (n < N_NODES) {
    if (c < XF) {
      val = x[(size_t)n * XF + c];
    } else if (c < XF + UF) {
      val = u[batch[n] * UF + (c - XF)];
    } else {
      int f = (c - (XF + UF)) & 63;
      int kind = (c - (XF + UF)) >> 6;   // 0: max, 1: mean, 2: sum
      float ct = cnt[n];
      if (kind == 0) {
        if (ct > 0.f) {
          unsigned enc = smax[(size_t)n * EF + f];
          unsigned bits = (enc >> 31) ? (enc ^ 0x80000000u) : ~enc;
          val = __uint_as_float(bits);
        }
      } else if (kind == 1) {
        val = ssum[(size_t)n * EF + f] / fmaxf(ct, 1.f);
      } else {
        val = ssum[(size_t)n * EF + f];
      }
    }
  }
  h[(size_t)n * CIN + c] = f2bf(val);
}

// ---------------------------------------------------------------------------
// 4) GEMM: C[M,1024] = A[M,K] @ B[1024,K]^T + bias, A/B bf16 row-major.
//    m97 structure: 128x128 block tile, 4 waves each 64x64 (4x4 of 16x16x32
//    MFMA), BK=32, global_load_lds width=16, unpadded [128][32] LDS tiles.
// ---------------------------------------------------------------------------
template <bool BF16OUT>
__global__ __launch_bounds__(256) void gemm_bt(
    const short* __restrict__ A, const short* __restrict__ B,
    const float* __restrict__ bias, void* __restrict__ outp, int K,
    int M_store) {
  __shared__ short aT[128 * 32];
  __shared__ short bT[128 * 32];
  const int tid = threadIdx.x;
  const int lane = tid & 63;
  const int wave = tid >> 6;
  const int m0 = blockIdx.y * 128;
  const int n0 = blockIdx.x * 128;
  const int wm = (wave & 1) * 64;
  const int wn = (wave >> 1) * 64;
  const int lm = lane & 15;
  const int lk8 = (lane >> 4) * 8;

  f32x4 acc[4][4];
#pragma unroll
  for (int i = 0; i < 4; ++i)
#pragma unroll
    for (int j = 0; j < 4; ++j) acc[i][j] = (f32x4){0.f, 0.f, 0.f, 0.f};

  // staging: 256 threads x 2 chunks x 8 bf16 = 128x32 tile, LDS contiguous
  const int q0 = tid;
  const int q1 = tid + 256;
  const short* ga0 = A + (size_t)(m0 + (q0 >> 2)) * K + (q0 & 3) * 8;
  const short* ga1 = A + (size_t)(m0 + (q1 >> 2)) * K + (q1 & 3) * 8;
  const short* gb0 = B + (size_t)(n0 + (q0 >> 2)) * K + (q0 & 3) * 8;
  const short* gb1 = B + (size_t)(n0 + (q1 >> 2)) * K + (q1 & 3) * 8;
  short* la0 = &aT[q0 * 8];
  short* la1 = &aT[q1 * 8];
  short* lb0 = &bT[q0 * 8];
  short* lb1 = &bT[q1 * 8];

  int aoff[4], boff[4];
#pragma unroll
  for (int t = 0; t < 4; ++t) {
    aoff[t] = (wm + t * 16 + lm) * 32 + lk8;
    boff[t] = (wn + t * 16 + lm) * 32 + lk8;
  }

  for (int k0 = 0; k0 < K; k0 += 32) {
    __syncthreads();
    ASYNC_CP(ga0 + k0, la0);
    ASYNC_CP(ga1 + k0, la1);
    ASYNC_CP(gb0 + k0, lb0);
    ASYNC_CP(gb1 + k0, lb1);
    __syncthreads();   // compiler drains vmcnt before s_barrier
    bf16x8 af[4], bfr[4];
#pragma unroll
    for (int t = 0; t < 4; ++t) {
      af[t] = __builtin_bit_cast(bf16x8, *(const s16x8*)&aT[aoff[t]]);
      bfr[t] = __builtin_bit_cast(bf16x8, *(const s16x8*)&bT[boff[t]]);
    }
#pragma unroll
    for (int i = 0; i < 4; ++i)
#pragma unroll
      for (int j = 0; j < 4; ++j)
        acc[i][j] = __builtin_amdgcn_mfma_f32_16x16x32_bf16(af[i], bfr[j],
                                                            acc[i][j], 0, 0, 0);
  }

  // epilogue: C/D layout col=lane&15, row=(lane>>4)*4+reg  [m89-verified]
#pragma unroll
  for (int j = 0; j < 4; ++j) {
    const int colg = n0 + wn + j * 16 + lm;
    const float bv = bias[colg];
#pragma unroll
    for (int i = 0; i < 4; ++i) {
      const int rbase = m0 + wm + i * 16 + (lane >> 4) * 4;
#pragma unroll
      for (int r = 0; r < 4; ++r) {
        const int row = rbase + r;
        if (row < M_store) {
          const float v = acc[i][j][r] + bv;
          if (BF16OUT)
            ((short*)outp)[(size_t)row * HS + colg] = f2bf(v);
          else
            ((float*)outp)[(size_t)row * HS + colg] = v;
        }
      }
    }
  }
}

// ---------------------------------------------------------------------------
// 5) BN stats: per-channel sum / sumsq over rows (atomic partials)
// ---------------------------------------------------------------------------
__global__ void stats_bf16_kernel(const short* __restrict__ y,
                                  float* __restrict__ sums, int rowsPerBlock) {
  const int c = blockIdx.x * 256 + threadIdx.x;
  int r0 = blockIdx.y * rowsPerBlock;
  int r1 = r0 + rowsPerBlock;
  if (r1 > N_NODES) r1 = N_NODES;
  float s = 0.f, q = 0.f;
  for (int r = r0; r < r1; ++r) {
    float v = bf2f(y[(size_t)r * HS + c]);
    s += v;
    q += v * v;
  }
  atomicAdd(&sums[c], s);
  atomicAdd(&sums[HS + c], q);
}

__global__ void stats_f32_kernel(const float* __restrict__ y,
                                 float* __restrict__ sums, int rowsPerBlock) {
  const int c = blockIdx.x * 256 + threadIdx.x;
  int r0 = blockIdx.y * rowsPerBlock;
  int r1 = r0 + rowsPerBlock;
  if (r1 > N_NODES) r1 = N_NODES;
  float s = 0.f, q = 0.f;
  for (int r = r0; r < r1; ++r) {
    float v = y[(size_t)r * HS + c];
    s += v;
    q += v * v;
  }
  atomicAdd(&sums[c], s);
  atomicAdd(&sums[HS + c], q);
}

__global__ void finalize_kernel(const float* __restrict__ sums,
                                const float* __restrict__ gamma,
                                const float* __restrict__ beta,
                                float* __restrict__ scsh) {
  int c = blockIdx.x * 256 + threadIdx.x;   // grid 4 x 256 = 1024
  const float inv = 1.f / (float)N_NODES;
  float m = sums[c] * inv;
  float var = sums[HS + c] * inv - m * m;   // biased var, matches reference
  float sc = gamma[c] / sqrtf(var + EPS_BN);
  scsh[c] = sc;
  scsh[HS + c] = beta[c] - m * sc;
}

// ---------------------------------------------------------------------------
// 6) BN apply (in place). bf16 variant adds ReLU (layer 1), f32 variant none.
// ---------------------------------------------------------------------------
__global__ void bn_relu_bf16_kernel(short* __restrict__ y,
                                    const float* __restrict__ scsh) {
  size_t base = (size_t)blockIdx.x * HS;
#pragma unroll
  for (int k = 0; k < 4; ++k) {
    int c = threadIdx.x + k * 256;
    float v = bf2f(y[base + c]) * scsh[c] + scsh[HS + c];
    y[base + c] = f2bf(fmaxf(v, 0.f));
  }
}

__global__ void bn_f32_kernel(float* __restrict__ y,
                              const float* __restrict__ scsh) {
  size_t base = (size_t)blockIdx.x * HS;
#pragma unroll
  for (int k = 0; k < 4; ++k) {
    int c = threadIdx.x + k * 256;
    y[base + c] = y[base + c] * scsh[c] + scsh[HS + c];
  }
}

// ---------------------------------------------------------------------------
extern "C" void kernel_launch(void* const* d_in, const int* in_sizes, int n_in,
                              void* d_out, int out_size, void* d_ws,
                              size_t ws_size, hipStream_t stream) {
  const float* x = (const float*)d_in[0];
  const float* ea = (const float*)d_in[1];
  const float* u = (const float*)d_in[2];
  const float* w1 = (const float*)d_in[3];
  const float* b1 = (const float*)d_in[4];
  const float* g1 = (const float*)d_in[5];
  const float* be1 = (const float*)d_in[6];
  const float* w2 = (const float*)d_in[7];
  const float* b2 = (const float*)d_in[8];
  const float* g2 = (const float*)d_in[9];
  const float* be2 = (const float*)d_in[10];
  const int* ei = (const int*)d_in[11];
  const int* batch = (const int*)d_in[12];
  float* out = (float*)d_out;

  // workspace layout (~215.4 MB total)
  char* ws = (char*)d_ws;
  float* sums = (float*)ws;                        // 2048 f32
  float* scsh = sums + 2048;                       // 2048 f32
  float* cnt = scsh + 2048;                        // 50048 f32 (padded)
  unsigned* smax = (unsigned*)(cnt + 50048);       // N*64
  float* ssum = (float*)(smax + (size_t)N_NODES * EF);
  short* h = (short*)(ssum + (size_t)N_NODES * EF);        // M_PAD*832 bf16
  short* w1b = h + (size_t)M_PAD * CIN;                    // 1024*832
  short* w2b = w1b + (size_t)HS * CIN;                     // 1024*1024
  short* y1 = w2b + (size_t)HS * HS;                       // M_PAD*1024 bf16

  // zero sums/scsh/cnt/smax/ssum in one shot (smax enc(0)=min works with the
  // order-preserving encoding; empties resolved via cnt)
  size_t zero_bytes = (size_t)((char*)h - ws);
  hipMemsetAsync(ws, 0, zero_bytes, stream);

  scatter_kernel<<<(N_EDGES * EF) / 256, 256, 0, stream>>>(ea, ei + N_EDGES,
                                                           ssum, smax, cnt);
  cast_kernel<<<(HS * CIN + 255) / 256, 256, 0, stream>>>(w1, w1b, HS * CIN);
  cast_kernel<<<(HS * HS + 255) / 256, 256, 0, stream>>>(w2, w2b, HS * HS);
  assemble_kernel<<<M_PAD, 832, 0, stream>>>(x, u, batch, cnt, smax, ssum, h);

  gemm_bt<true><<<dim3(8, M_PAD / 128), 256, 0, stream>>>(h, w1b, b1, y1, CIN,
                                                          M_PAD);
  stats_bf16_kernel<<<dim3(4, 125), 256, 0, stream>>>(y1, sums, 400);
  finalize_kernel<<<4, 256, 0, stream>>>(sums, g1, be1, scsh);
  bn_relu_bf16_kernel<<<N_NODES, 256, 0, stream>>>(y1, scsh);

  gemm_bt<false><<<dim3(8, M_PAD / 128), 256, 0, stream>>>(y1, w2b, b2, out,
                                                           HS, N_NODES);
  hipMemsetAsync(sums, 0, 2048 * sizeof(float), stream);
  stats_f32_kernel<<<dim3(4, 125), 256, 0, stream>>>(out, sums, 400);
  finalize_kernel<<<4, 256, 0, stream>>>(sums, g2, be2, scsh);
  bn_f32_kernel<<<N_NODES, 256, 0, stream>>>(out, scsh);
}

// Round 2
// 1051.839 us; speedup vs baseline: 1.4142x; 1.4142x over previous
//
#include <hip/hip_runtime.h>

// Problem constants (from reference setup_inputs)
#define N_NODES 50000
#define N_EDGES 800000
#define XF 512
#define EF 64
#define UF 128
#define HS 1024
#define CIN 832           // 512 + 3*64 + 128
#define EPS_BN 1e-5f
#define M_PAD 50048       // 391 * 128  (GEMM row padding)
#define NSCAN 50176       // 196 * 256  (scan padding)

typedef __bf16 bf16x8 __attribute__((ext_vector_type(8)));
typedef short s16x8 __attribute__((ext_vector_type(8)));
typedef short s16x4 __attribute__((ext_vector_type(4)));
typedef float f32x4 __attribute__((ext_vector_type(4)));

__device__ __forceinline__ short f2bf(float f) {
  unsigned u = __float_as_uint(f);
  u += 0x7FFFu + ((u >> 16) & 1u);   // round-to-nearest-even (finite inputs)
  return (short)(u >> 16);
}
__device__ __forceinline__ float bf2f(short s) {
  return __uint_as_float(((unsigned)(unsigned short)s) << 16);
}

// async global->LDS, 16B per lane; LDS dest must be uniform-base + lane*16
#define ASYNC_CP(gp, lp)                                                      \
  __builtin_amdgcn_global_load_lds(                                           \
      (__attribute__((address_space(1))) void*)(gp),                          \
      (__attribute__((address_space(3))) void*)(lp), 16, 0, 0)

// ---------------------------------------------------------------------------
// 1) Edge histogram over destination node (int atomics, 1 per edge)
// ---------------------------------------------------------------------------
__global__ void hist_kernel(const int* __restrict__ col,
                            int* __restrict__ hist) {
  int e = blockIdx.x * 256 + threadIdx.x;   // grid exactly E
  atomicAdd(&hist[col[e]], 1);
}

// ---------------------------------------------------------------------------
// 2) 3-phase exclusive scan over NSCAN counts
// ---------------------------------------------------------------------------
__global__ void scan1_kernel(const int* __restrict__ hist,
                             int* __restrict__ starts,
                             int* __restrict__ bsum) {
  __shared__ int tmp[256];
  int i = blockIdx.x * 256 + threadIdx.x;
  int v = hist[i];
  tmp[threadIdx.x] = v;
  __syncthreads();
#pragma unroll
  for (int o = 1; o < 256; o <<= 1) {
    int t = (threadIdx.x >= o) ? tmp[threadIdx.x - o] : 0;
    __syncthreads();
    tmp[threadIdx.x] += t;
    __syncthreads();
  }
  starts[i] = tmp[threadIdx.x] - v;   // exclusive
  if (threadIdx.x == 255) bsum[blockIdx.x] = tmp[255];
}

__global__ void scan2_kernel(const int* __restrict__ bsum,
                             int* __restrict__ boff) {
  __shared__ int tmp[256];
  int v = (threadIdx.x < NSCAN / 256) ? bsum[threadIdx.x] : 0;
  tmp[threadIdx.x] = v;
  __syncthreads();
#pragma unroll
  for (int o = 1; o < 256; o <<= 1) {
    int t = (threadIdx.x >= o) ? tmp[threadIdx.x - o] : 0;
    __syncthreads();
    tmp[threadIdx.x] += t;
    __syncthreads();
  }
  boff[threadIdx.x] = tmp[threadIdx.x] - v;
}

__global__ void scan3_kernel(int* __restrict__ starts,
                             const int* __restrict__ boff,
                             int* __restrict__ cursor) {
  int i = blockIdx.x * 256 + threadIdx.x;
  int s = starts[i] + boff[blockIdx.x];
  starts[i] = s;
  cursor[i] = s;
}

// ---------------------------------------------------------------------------
// 3) Placement: edge ids sorted (bucketed) by destination node
// ---------------------------------------------------------------------------
__global__ void place_kernel(const int* __restrict__ col,
                             int* __restrict__ cursor,
                             int* __restrict__ sortedEid) {
  int e = blockIdx.x * 256 + threadIdx.x;   // grid exactly E
  int c = col[e];
  int pos = atomicAdd(&cursor[c], 1);
  sortedEid[pos] = e;
}

// ---------------------------------------------------------------------------
// 4) Segmented reduce: one wave per node; lane = feature. Each iteration the
//    wave reads one contiguous 256B edge row. Writes max/mean/sum cols of h.
// ---------------------------------------------------------------------------
__global__ __launch_bounds__(256) void edge_reduce_kernel(
    const float* __restrict__ ea, const int* __restrict__ sortedEid,
    const int* __restrict__ hist, const int* __restrict__ starts,
    short* __restrict__ h) {
  int node = blockIdx.x * 4 + (threadIdx.x >> 6);   // grid 12500 -> node<50000
  int lane = threadIdx.x & 63;
  int deg = hist[node];
  int st = starts[node];
  float s = 0.f, mx = -3.0e38f;
  for (int i = 0; i < deg; ++i) {
    int e = sortedEid[st + i];
    float v = ea[(size_t)e * EF + lane];
    s += v;
    mx = fmaxf(mx, v);
  }
  size_t base = (size_t)node * CIN;
  h[base + 640 + lane] = f2bf(deg ? mx : 0.f);
  h[base + 704 + lane] = f2bf(deg ? s / (float)deg : 0.f);
  h[base + 768 + lane] = f2bf(s);
}

// ---------------------------------------------------------------------------
// 5) Assemble x / u[batch] columns of h (bf16), zero pad rows entirely
// ---------------------------------------------------------------------------
__global__ __launch_bounds__(256) void assemble_xu_kernel(
    const float* __restrict__ x, const float* __restrict__ u,
    const int* __restrict__ batch, short* __restrict__ h) {
  int n = blockIdx.x;
  int t = threadIdx.x;
  size_t base = (size_t)n * CIN;
  if (n >= N_NODES) {           // pad rows: zero all 832 cols
    if (t < 208) *(s16x4*)&h[base + 4 * t] = (s16x4){0, 0, 0, 0};
    return;
  }
  if (t < 128) {
    const float4 v = *(const float4*)&x[(size_t)n * XF + 4 * t];
    *(s16x4*)&h[base + 4 * t] =
        (s16x4){f2bf(v.x), f2bf(v.y), f2bf(v.z), f2bf(v.w)};
  } else if (t < 160) {
    int c = 4 * (t - 128);
    const float4 v = *(const float4*)&u[batch[n] * UF + c];
    *(s16x4*)&h[base + XF + c] =
        (s16x4){f2bf(v.x), f2bf(v.y), f2bf(v.z), f2bf(v.w)};
  }
}

// ---------------------------------------------------------------------------
// 6) fp32 -> bf16 weight cast
// ---------------------------------------------------------------------------
__global__ void cast_kernel(const float* __restrict__ w, short* __restrict__ o,
                            int n) {
  int i = blockIdx.x * 256 + threadIdx.x;
  if (i < n) o[i] = f2bf(w[i]);
}

// ---------------------------------------------------------------------------
// 7) GEMM: C[M,1024] = A[M,K] @ B[1024,K]^T + bias, bf16 in, fused BN stats.
//    m97 structure: 128x128 tile, 4 waves of 64x64 (4x4 MFMA 16x16x32), BK=32.
// ---------------------------------------------------------------------------
template <bool BF16OUT>
__global__ __launch_bounds__(256) void gemm_bt(
    const short* __restrict__ A, const short* __restrict__ B,
    const float* __restrict__ bias, void* __restrict__ outp, int K,
    int M_store, int M_stat, float* __restrict__ sums) {
  __shared__ short aT[128 * 32];
  __shared__ short bT[128 * 32];
  const int tid = threadIdx.x;
  const int lane = tid & 63;
  const int wave = tid >> 6;
  const int m0 = blockIdx.y * 128;
  const int n0 = blockIdx.x * 128;
  const int wm = (wave & 1) * 64;
  const int wn = (wave >> 1) * 64;
  const int lm = lane & 15;
  const int lk8 = (lane >> 4) * 8;

  f32x4 acc[4][4];
#pragma unroll
  for (int i = 0; i < 4; ++i)
#pragma unroll
    for (int j = 0; j < 4; ++j) acc[i][j] = (f32x4){0.f, 0.f, 0.f, 0.f};

  const int q0 = tid;
  const int q1 = tid + 256;
  const short* ga0 = A + (size_t)(m0 + (q0 >> 2)) * K + (q0 & 3) * 8;
  const short* ga1 = A + (size_t)(m0 + (q1 >> 2)) * K + (q1 & 3) * 8;
  const short* gb0 = B + (size_t)(n0 + (q0 >> 2)) * K + (q0 & 3) * 8;
  const short* gb1 = B + (size_t)(n0 + (q1 >> 2)) * K + (q1 & 3) * 8;
  short* la0 = &aT[q0 * 8];
  short* la1 = &aT[q1 * 8];
  short* lb0 = &bT[q0 * 8];
  short* lb1 = &bT[q1 * 8];

  int aoff[4], boff[4];
#pragma unroll
  for (int t = 0; t < 4; ++t) {
    aoff[t] = (wm + t * 16 + lm) * 32 + lk8;
    boff[t] = (wn + t * 16 + lm) * 32 + lk8;
  }

  for (int k0 = 0; k0 < K; k0 += 32) {
    __syncthreads();
    ASYNC_CP(ga0 + k0, la0);
    ASYNC_CP(ga1 + k0, la1);
    ASYNC_CP(gb0 + k0, lb0);
    ASYNC_CP(gb1 + k0, lb1);
    __syncthreads();
    bf16x8 af[4], bfr[4];
#pragma unroll
    for (int t = 0; t < 4; ++t) {
      af[t] = __builtin_bit_cast(bf16x8, *(const s16x8*)&aT[aoff[t]]);
      bfr[t] = __builtin_bit_cast(bf16x8, *(const s16x8*)&bT[boff[t]]);
    }
#pragma unroll
    for (int i = 0; i < 4; ++i)
#pragma unroll
      for (int j = 0; j < 4; ++j)
        acc[i][j] = __builtin_amdgcn_mfma_f32_16x16x32_bf16(af[i], bfr[j],
                                                            acc[i][j], 0, 0, 0);
  }

  // epilogue: C/D layout col=lane&15, row=(lane>>4)*4+reg  [m89-verified]
  // + fused per-channel sum / sumsq partials for BN (rows < M_stat)
#pragma unroll
  for (int j = 0; j < 4; ++j) {
    const int colg = n0 + wn + j * 16 + lm;
    const float bv = bias[colg];
    float cs = 0.f, cq = 0.f;
#pragma unroll
    for (int i = 0; i < 4; ++i) {
      const int rbase = m0 + wm + i * 16 + (lane >> 4) * 4;
#pragma unroll
      for (int r = 0; r < 4; ++r) {
        const int row = rbase + r;
        const float v = acc[i][j][r] + bv;
        if (row < M_stat) {
          cs += v;
          cq += v * v;
        }
        if (row < M_store) {
          if (BF16OUT)
            ((short*)outp)[(size_t)row * HS + colg] = f2bf(v);
          else
            ((float*)outp)[(size_t)row * HS + colg] = v;
        }
      }
    }
    cs += __shfl_xor(cs, 16);
    cs += __shfl_xor(cs, 32);
    cq += __shfl_xor(cq, 16);
    cq += __shfl_xor(cq, 32);
    if ((lane >> 4) == 0) {
      atomicAdd(&sums[colg], cs);
      atomicAdd(&sums[HS + colg], cq);
    }
  }
}

// ---------------------------------------------------------------------------
// 8) BN finalize: per-channel scale/shift from sums
// ---------------------------------------------------------------------------
__global__ void finalize_kernel(const float* __restrict__ sums,
                                const float* __restrict__ gamma,
                                const float* __restrict__ beta,
                                float* __restrict__ scsh) {
  int c = blockIdx.x * 256 + threadIdx.x;   // grid 4 x 256 = 1024
  const float inv = 1.f / (float)N_NODES;
  float m = sums[c] * inv;
  float var = sums[HS + c] * inv - m * m;   // biased var, matches reference
  float sc = gamma[c] / sqrtf(var + EPS_BN);
  scsh[c] = sc;
  scsh[HS + c] = beta[c] - m * sc;
}

// ---------------------------------------------------------------------------
// 9) BN apply (in place). bf16 variant adds ReLU (layer 1).
// ---------------------------------------------------------------------------
__global__ __launch_bounds__(256) void bn_relu_bf16_kernel(
    short* __restrict__ y, const float* __restrict__ scsh) {
  size_t base = (size_t)blockIdx.x * HS + threadIdx.x * 4;
  int c = threadIdx.x * 4;
  s16x4 v = *(s16x4*)&y[base];
  s16x4 o;
#pragma unroll
  for (int k = 0; k < 4; ++k) {
    float f = bf2f(v[k]) * scsh[c + k] + scsh[HS + c + k];
    o[k] = f2bf(fmaxf(f, 0.f));
  }
  *(s16x4*)&y[base] = o;
}

__global__ __launch_bounds__(256) void bn_f32_kernel(
    float* __restrict__ y, const float* __restrict__ scsh) {
  size_t base = (size_t)blockIdx.x * HS + threadIdx.x * 4;
  int c = threadIdx.x * 4;
  float4 v = *(float4*)&y[base];
  const float4 sc = *(const float4*)&scsh[c];
  const float4 sh = *(const float4*)&scsh[HS + c];
  v.x = v.x * sc.x + sh.x;
  v.y = v.y * sc.y + sh.y;
  v.z = v.z * sc.z + sh.z;
  v.w = v.w * sc.w + sh.w;
  *(float4*)&y[base] = v;
}

// ---------------------------------------------------------------------------
extern "C" void kernel_launch(void* const* d_in, const int* in_sizes, int n_in,
                              void* d_out, int out_size, void* d_ws,
                              size_t ws_size, hipStream_t stream) {
  const float* x = (const float*)d_in[0];
  const float* ea = (const float*)d_in[1];
  const float* u = (const float*)d_in[2];
  const float* w1 = (const float*)d_in[3];
  const float* b1 = (const float*)d_in[4];
  const float* g1 = (const float*)d_in[5];
  const float* be1 = (const float*)d_in[6];
  const float* w2 = (const float*)d_in[7];
  const float* b2 = (const float*)d_in[8];
  const float* g2 = (const float*)d_in[9];
  const float* be2 = (const float*)d_in[10];
  const int* ei = (const int*)d_in[11];
  const int* batch = (const int*)d_in[12];
  float* out = (float*)d_out;
  const int* col = ei + N_EDGES;   // edge_index[1]

  // ---- workspace layout ----
  char* ws = (char*)d_ws;
  float* sums1 = (float*)ws;                     // 2048
  float* sums2 = sums1 + 2048;                   // 2048
  int* hist = (int*)(sums2 + 2048);              // NSCAN
  int* bsum = hist + NSCAN;                      // 256
  // ---- end of zero region ----
  size_t zero_bytes = (size_t)((char*)(bsum + 256) - ws);
  float* scsh = (float*)(bsum + 256);            // 2048
  int* starts = (int*)(scsh + 2048);             // NSCAN
  int* cursor = starts + NSCAN;                  // NSCAN
  int* boff = cursor + NSCAN;                    // 256
  int* sortedEid = boff + 256;                   // N_EDGES
  char* hraw = (char*)(sortedEid + N_EDGES);
  short* h = (short*)(((uintptr_t)hraw + 255) & ~(uintptr_t)255);
  short* w1b = h + (size_t)M_PAD * CIN;
  short* w2b = w1b + (size_t)HS * CIN;
  short* y1 = w2b + (size_t)HS * HS;

  hipMemsetAsync(ws, 0, zero_bytes, stream);

  // edge bucketing
  hist_kernel<<<N_EDGES / 256, 256, 0, stream>>>(col, hist);
  scan1_kernel<<<NSCAN / 256, 256, 0, stream>>>(hist, starts, bsum);
  scan2_kernel<<<1, 256, 0, stream>>>(bsum, boff);
  scan3_kernel<<<NSCAN / 256, 256, 0, stream>>>(starts, boff, cursor);
  place_kernel<<<N_EDGES / 256, 256, 0, stream>>>(col, cursor, sortedEid);

  // h assembly
  assemble_xu_kernel<<<M_PAD, 256, 0, stream>>>(x, u, batch, h);
  edge_reduce_kernel<<<N_NODES / 4, 256, 0, stream>>>(ea, sortedEid, hist,
                                                      starts, h);
  cast_kernel<<<(HS * CIN + 255) / 256, 256, 0, stream>>>(w1, w1b, HS * CIN);
  cast_kernel<<<(HS * HS + 255) / 256, 256, 0, stream>>>(w2, w2b, HS * HS);

  // layer 1
  gemm_bt<true><<<dim3(8, M_PAD / 128), 256, 0, stream>>>(
      h, w1b, b1, y1, CIN, M_PAD, N_NODES, sums1);
  finalize_kernel<<<4, 256, 0, stream>>>(sums1, g1, be1, scsh);
  bn_relu_bf16_kernel<<<N_NODES, 256, 0, stream>>>(y1, scsh);

  // layer 2
  gemm_bt<false><<<dim3(8, M_PAD / 128), 256, 0, stream>>>(
      y1, w2b, b2, out, HS, N_NODES, N_NODES, sums2);
  finalize_kernel<<<4, 256, 0, stream>>>(sums2, g2, be2, scsh);
  bn_f32_kernel<<<N_NODES, 256, 0, stream>>>(out, scsh);
}